// Round 1
// baseline (2678.213 us; speedup 1.0000x reference)
//
#include <hip/hip_runtime.h>
#include <cstdint>
#include <cstddef>

// ---------------------------------------------------------------------------
// DualAttention: B=1024, L=196, H=1024, A=512
//   spatial  = att @ W_att + b_att            [B,L,A]   (fused, never stored)
//   channel  = att^T_l @ W_ch + b_ch          [B,H,A]   (fused, never stored)
//   p_h      = h @ W_h + b_h                  [B,A]
//   logits_s = tanh(spatial + p_h) . w_alpha  [B,L]  -> softmax_L -> w_spatial
//   logits_c = tanh(channel + p_h) . w_beta   [B,H]  -> softmax_H -> w_channel
//   out0 = sum_l w_spatial * att  [B,H]
//   out1 = sum_h w_channel * att  [B,L]
//   out2 = w_spatial              [B,L]
// ---------------------------------------------------------------------------

#define DEVI __device__ __forceinline__

typedef __bf16 bf16;
typedef bf16 bf16x4 __attribute__((ext_vector_type(4)));
typedef bf16 bf16x8 __attribute__((ext_vector_type(8)));
typedef float f32x4 __attribute__((ext_vector_type(4)));

static constexpr int Bb = 1024;
static constexpr int Ll = 196;
static constexpr int Hh = 1024;
static constexpr int Aa = 512;
static constexpr int BL = Bb * Ll;        // 200704
static constexpr int LPAD = 224;          // 196 padded to 7*32

// LDS geometry for the two GEMM kernels: 64-row A tile + 512-row B tile,
// both 32 K-columns of bf16 (64B data) padded to 80B stride (5x16B -> frag
// reads hit 8 distinct banks, 2-way conflict = free).
#define A_STRIDE 80
#define B_OFF    5120            /* 64*80 */
#define LDS_SZ   46080           /* 5120 + 512*80 */

DEVI float fast_tanh(float x) {
  float e = __expf(2.f * x);
  return 1.f - 2.f * __builtin_amdgcn_rcpf(e + 1.f);
}

// --------------------------- weight pre-transposes -------------------------
// W_att [H=1024, A=512] fp32 -> Wt [A=512][1024] bf16
__global__ void k_transpose_watt(const float* __restrict__ W, bf16* __restrict__ Wt) {
  int idx = blockIdx.x * 256 + threadIdx.x;      // 512*1024 threads
  int a = idx & 511;
  int k = idx >> 9;
  Wt[(size_t)a * 1024 + k] = (bf16)W[(size_t)k * 512 + a];
}

// W_ch [L=196, A=512] fp32 -> Wct [A=512][224] bf16, zero-padded K
__global__ void k_transpose_wch(const float* __restrict__ W, bf16* __restrict__ Wt) {
  int idx = blockIdx.x * 256 + threadIdx.x;      // 512*224 threads
  int a = idx & 511;
  int l = idx >> 9;                              // 0..223
  float v = (l < Ll) ? W[(size_t)l * 512 + a] : 0.f;
  Wt[(size_t)a * LPAD + l] = (bf16)v;
}

// ------------------------------- p_h = h@W_h -------------------------------
__global__ void k_ph(const float* __restrict__ h, const float* __restrict__ W_h,
                     const float* __restrict__ b_h, float* __restrict__ p_h) {
  int a = blockIdx.x * 256 + threadIdx.x;        // gridDim.x = 2
  int b0 = blockIdx.y * 8;                       // gridDim.y = 128
  float acc[8] = {0.f, 0.f, 0.f, 0.f, 0.f, 0.f, 0.f, 0.f};
  for (int k = 0; k < 1024; ++k) {
    float w = W_h[(size_t)k * 512 + a];
#pragma unroll
    for (int i = 0; i < 8; ++i) acc[i] += h[(size_t)(b0 + i) * 1024 + k] * w;
  }
#pragma unroll
  for (int i = 0; i < 8; ++i) p_h[(size_t)(b0 + i) * 512 + a] = acc[i] + b_h[a];
}

// ---------------- spatial branch: fused GEMM + tanh-dot reduce -------------
// grid = BL/64 = 3136 blocks, 256 threads (4 waves; wave wn owns cols wn*128..+127)
__launch_bounds__(256)
__global__ void k_spatial(const float* __restrict__ att, const bf16* __restrict__ Wt,
                          const float* __restrict__ b_att, const float* __restrict__ p_h,
                          const float* __restrict__ w_alpha, float* __restrict__ logits_s) {
  __shared__ alignas(16) char lds[LDS_SZ];
  const int tid = threadIdx.x;
  const int lane = tid & 63;
  const int wn = tid >> 6;
  const int l15 = lane & 15, l4 = lane >> 4;
  const size_t row0 = (size_t)blockIdx.x * 64;

  f32x4 acc[4][8];
#pragma unroll
  for (int m = 0; m < 4; ++m)
#pragma unroll
    for (int n = 0; n < 8; ++n) acc[m][n] = f32x4{0.f, 0.f, 0.f, 0.f};

  for (int k0 = 0; k0 < 1024; k0 += 32) {
    // stage A: 64 rows x 32 k, fp32 -> bf16 (reg-staged; conversion needed)
#pragma unroll
    for (int i = 0; i < 2; ++i) {
      int f = tid + 256 * i;                     // 0..511
      int r = f >> 3;                            // 0..63
      int k4 = (f & 7) << 2;                     // 0,4,..,28
      float4 v = *reinterpret_cast<const float4*>(&att[(row0 + r) * 1024 + k0 + k4]);
      bf16x4 pk = {(bf16)v.x, (bf16)v.y, (bf16)v.z, (bf16)v.w};
      *reinterpret_cast<bf16x4*>(&lds[r * A_STRIDE + (k4 << 1)]) = pk;
    }
    // stage B: Wt rows 0..511 x 32 k (bf16, 16B chunks)
#pragma unroll
    for (int i = 0; i < 8; ++i) {
      int f = tid + 256 * i;                     // 0..2047
      int r = f >> 2;                            // 0..511
      int c16 = (f & 3) << 4;
      uint4 v = *reinterpret_cast<const uint4*>(
          reinterpret_cast<const char*>(Wt) + (((size_t)r << 10) + k0) * 2 + c16);
      *reinterpret_cast<uint4*>(&lds[B_OFF + r * A_STRIDE + c16]) = v;
    }
    __syncthreads();

    bf16x8 af[4];
#pragma unroll
    for (int m = 0; m < 4; ++m)
      af[m] = *reinterpret_cast<const bf16x8*>(&lds[(m * 16 + l15) * A_STRIDE + (l4 << 4)]);
#pragma unroll
    for (int n = 0; n < 8; ++n) {
      int cc = wn * 128 + n * 16 + l15;
      bf16x8 bf = *reinterpret_cast<const bf16x8*>(&lds[B_OFF + cc * A_STRIDE + (l4 << 4)]);
#pragma unroll
      for (int m = 0; m < 4; ++m)
        acc[m][n] = __builtin_amdgcn_mfma_f32_16x16x32_bf16(af[m], bf, acc[m][n], 0, 0, 0);
    }
    __syncthreads();
  }

  // epilogue: logits_s[row] = sum_a tanh(spatial + p_h) * w_alpha   (fp32)
  float wa[8], ba[8];
  int cols[8];
#pragma unroll
  for (int n = 0; n < 8; ++n) {
    int a = wn * 128 + n * 16 + l15;
    cols[n] = a;
    wa[n] = w_alpha[a];
    ba[n] = b_att[a];
  }
  float* red = reinterpret_cast<float*>(lds);    // [4][64]
#pragma unroll
  for (int m = 0; m < 4; ++m) {
#pragma unroll
    for (int j = 0; j < 4; ++j) {
      int rloc = m * 16 + l4 * 4 + j;
      unsigned R = (unsigned)row0 + rloc;
      unsigned bidx = R / 196u;
      const float* phr = p_h + (size_t)bidx * 512;
      float s = 0.f;
#pragma unroll
      for (int n = 0; n < 8; ++n)
        s += fast_tanh(acc[m][n][j] + ba[n] + phr[cols[n]]) * wa[n];
      s += __shfl_xor(s, 1);
      s += __shfl_xor(s, 2);
      s += __shfl_xor(s, 4);
      s += __shfl_xor(s, 8);
      if (l15 == 0) red[wn * 64 + rloc] = s;
    }
  }
  __syncthreads();
  if (tid < 64)
    logits_s[row0 + tid] = red[tid] + red[64 + tid] + red[128 + tid] + red[192 + tid];
}

// ---------------- channel branch: fused GEMM + tanh-dot reduce -------------
// grid = (H/64=16, B=1024), 256 threads. A-operand is att[b] transposed in LDS.
__launch_bounds__(256)
__global__ void k_channel(const float* __restrict__ att, const bf16* __restrict__ Wct,
                          const float* __restrict__ b_ch, const float* __restrict__ p_h,
                          const float* __restrict__ w_beta, float* __restrict__ logits_c) {
  __shared__ alignas(16) char lds[LDS_SZ];
  const int tid = threadIdx.x;
  const int lane = tid & 63;
  const int wn = tid >> 6;
  const int l15 = lane & 15, l4 = lane >> 4;
  const int b = blockIdx.y;
  const int h0 = blockIdx.x * 64;
  const float* attb = att + (size_t)b * Ll * 1024;

  f32x4 acc[4][8];
#pragma unroll
  for (int m = 0; m < 4; ++m)
#pragma unroll
    for (int n = 0; n < 8; ++n) acc[m][n] = f32x4{0.f, 0.f, 0.f, 0.f};

  for (int k0 = 0; k0 < LPAD; k0 += 32) {
    // stage A transposed: Alds[h 0..63][l 0..31] <- att[b][k0+l][h0+h]
    {
      int hh = tid & 63;
      int lg = tid >> 6;                         // 0..3 -> l = lg*8 + j
      float vals[8];
#pragma unroll
      for (int j = 0; j < 8; ++j) {
        int l = k0 + lg * 8 + j;
        vals[j] = (l < Ll) ? attb[(size_t)l * 1024 + h0 + hh] : 0.f;
      }
#pragma unroll
      for (int w = 0; w < 2; ++w) {
        bf16x4 pk = {(bf16)vals[4 * w], (bf16)vals[4 * w + 1],
                     (bf16)vals[4 * w + 2], (bf16)vals[4 * w + 3]};
        *reinterpret_cast<bf16x4*>(&lds[hh * A_STRIDE + ((lg * 8 + 4 * w) << 1)]) = pk;
      }
    }
    // stage B: Wct rows 0..511 x 32 l
#pragma unroll
    for (int i = 0; i < 8; ++i) {
      int f = tid + 256 * i;
      int r = f >> 2;
      int c16 = (f & 3) << 4;
      uint4 v = *reinterpret_cast<const uint4*>(
          reinterpret_cast<const char*>(Wct) + ((size_t)r * LPAD + k0) * 2 + c16);
      *reinterpret_cast<uint4*>(&lds[B_OFF + r * A_STRIDE + c16]) = v;
    }
    __syncthreads();

    bf16x8 af[4];
#pragma unroll
    for (int m = 0; m < 4; ++m)
      af[m] = *reinterpret_cast<const bf16x8*>(&lds[(m * 16 + l15) * A_STRIDE + (l4 << 4)]);
#pragma unroll
    for (int n = 0; n < 8; ++n) {
      int cc = wn * 128 + n * 16 + l15;
      bf16x8 bf = *reinterpret_cast<const bf16x8*>(&lds[B_OFF + cc * A_STRIDE + (l4 << 4)]);
#pragma unroll
      for (int m = 0; m < 4; ++m)
        acc[m][n] = __builtin_amdgcn_mfma_f32_16x16x32_bf16(af[m], bf, acc[m][n], 0, 0, 0);
    }
    __syncthreads();
  }

  // epilogue: logits_c[b,h] = sum_a tanh(channel + p_h[b]) * w_beta
  float wb[8], bc[8], ph[8];
#pragma unroll
  for (int n = 0; n < 8; ++n) {
    int a = wn * 128 + n * 16 + l15;
    wb[n] = w_beta[a];
    bc[n] = b_ch[a];
    ph[n] = p_h[(size_t)b * 512 + a];
  }
  float* red = reinterpret_cast<float*>(lds);
#pragma unroll
  for (int m = 0; m < 4; ++m) {
#pragma unroll
    for (int j = 0; j < 4; ++j) {
      int rloc = m * 16 + l4 * 4 + j;
      float s = 0.f;
#pragma unroll
      for (int n = 0; n < 8; ++n)
        s += fast_tanh(acc[m][n][j] + bc[n] + ph[n]) * wb[n];
      s += __shfl_xor(s, 1);
      s += __shfl_xor(s, 2);
      s += __shfl_xor(s, 4);
      s += __shfl_xor(s, 8);
      if (l15 == 0) red[wn * 64 + rloc] = s;
    }
  }
  __syncthreads();
  if (tid < 64)
    logits_c[(size_t)b * 1024 + h0 + tid] =
        red[tid] + red[64 + tid] + red[128 + tid] + red[192 + tid];
}

// ------------------------------- softmaxes ---------------------------------
__global__ void k_softmax_s(const float* __restrict__ logits, float* __restrict__ wout) {
  int b = blockIdx.x, t = threadIdx.x;           // 256 threads
  __shared__ float sm[8];
  float x = (t < Ll) ? logits[(size_t)b * Ll + t] : -1e30f;
  float m = x;
#pragma unroll
  for (int o = 32; o; o >>= 1) m = fmaxf(m, __shfl_xor(m, o));
  if ((t & 63) == 0) sm[t >> 6] = m;
  __syncthreads();
  m = fmaxf(fmaxf(sm[0], sm[1]), fmaxf(sm[2], sm[3]));
  float e = (t < Ll) ? __expf(x - m) : 0.f;
  float s = e;
#pragma unroll
  for (int o = 32; o; o >>= 1) s += __shfl_xor(s, o);
  if ((t & 63) == 0) sm[4 + (t >> 6)] = s;
  __syncthreads();
  s = sm[4] + sm[5] + sm[6] + sm[7];
  if (t < Ll) wout[(size_t)b * Ll + t] = e / s;
}

__global__ void k_softmax_c(const float* __restrict__ logits, float* __restrict__ wout) {
  int b = blockIdx.x, t = threadIdx.x;           // 256 threads x 4 elems
  __shared__ float sm[8];
  float4 x = *reinterpret_cast<const float4*>(&logits[(size_t)b * 1024 + (t << 2)]);
  float m = fmaxf(fmaxf(x.x, x.y), fmaxf(x.z, x.w));
#pragma unroll
  for (int o = 32; o; o >>= 1) m = fmaxf(m, __shfl_xor(m, o));
  if ((t & 63) == 0) sm[t >> 6] = m;
  __syncthreads();
  m = fmaxf(fmaxf(sm[0], sm[1]), fmaxf(sm[2], sm[3]));
  float e0 = __expf(x.x - m), e1 = __expf(x.y - m);
  float e2 = __expf(x.z - m), e3 = __expf(x.w - m);
  float s = e0 + e1 + e2 + e3;
#pragma unroll
  for (int o = 32; o; o >>= 1) s += __shfl_xor(s, o);
  if ((t & 63) == 0) sm[4 + (t >> 6)] = s;
  __syncthreads();
  float r = 1.f / (sm[4] + sm[5] + sm[6] + sm[7]);
  float4 o4 = {e0 * r, e1 * r, e2 * r, e3 * r};
  *reinterpret_cast<float4*>(&wout[(size_t)b * 1024 + (t << 2)]) = o4;
}

// --------------- fused weighted sums: one pass over att --------------------
// out0[b,h] = sum_l ws[b,l]*att[b,l,h];  out1[b,l] = sum_h wc[b,h]*att[b,l,h]
__launch_bounds__(256)
__global__ void k_weighted(const float* __restrict__ att, const float* __restrict__ wsp,
                           const float* __restrict__ wch, float* __restrict__ out_s,
                           float* __restrict__ out_c) {
  int b = blockIdx.x, t = threadIdx.x;
  int lane = t & 63, wave = t >> 6;
  __shared__ float wsl[Ll];
  __shared__ float chan[4][Ll];
  if (t < Ll) wsl[t] = wsp[(size_t)b * Ll + t];
  float4 wc = *reinterpret_cast<const float4*>(&wch[(size_t)b * 1024 + (t << 2)]);
  float4 accs = {0.f, 0.f, 0.f, 0.f};
  __syncthreads();
  const float* attb = att + (size_t)b * Ll * 1024;
  for (int l = 0; l < Ll; ++l) {
    float4 v = *reinterpret_cast<const float4*>(&attb[(size_t)l * 1024 + (t << 2)]);
    float w = wsl[l];
    accs.x += w * v.x; accs.y += w * v.y; accs.z += w * v.z; accs.w += w * v.w;
    float pc = wc.x * v.x + wc.y * v.y + wc.z * v.z + wc.w * v.w;
#pragma unroll
    for (int o = 32; o; o >>= 1) pc += __shfl_xor(pc, o);
    if (lane == 0) chan[wave][l] = pc;
  }
  *reinterpret_cast<float4*>(&out_s[(size_t)b * 1024 + (t << 2)]) = accs;
  __syncthreads();
  if (t < Ll)
    out_c[(size_t)b * Ll + t] = chan[0][t] + chan[1][t] + chan[2][t] + chan[3][t];
}

// ------------------------------- launcher ----------------------------------
extern "C" void kernel_launch(void* const* d_in, const int* in_sizes, int n_in,
                              void* d_out, int out_size, void* d_ws, size_t ws_size,
                              hipStream_t stream) {
  (void)in_sizes; (void)n_in; (void)out_size; (void)ws_size;
  const float* att     = (const float*)d_in[0];
  const float* h       = (const float*)d_in[1];
  const float* W_att   = (const float*)d_in[2];
  const float* b_att   = (const float*)d_in[3];
  const float* W_h     = (const float*)d_in[4];
  const float* b_h     = (const float*)d_in[5];
  const float* w_alpha = (const float*)d_in[6];
  // d_in[7] = b_alpha: softmax-shift-invariant, unused
  const float* W_ch    = (const float*)d_in[8];
  const float* b_ch    = (const float*)d_in[9];
  const float* w_beta  = (const float*)d_in[10];
  // d_in[11] = b_beta: softmax-shift-invariant, unused

  float* out_ws    = (float*)d_out;                       // [B,H]
  float* out_wc    = out_ws + (size_t)Bb * Hh;            // [B,L]
  float* out_wspat = out_wc + (size_t)Bb * Ll;            // [B,L]

  char* ws = (char*)d_ws;
  float* p_h      = (float*)(ws);                          // 2 MB
  float* logits_s = (float*)(ws + 2097152);                // 802816 B
  float* logits_c = (float*)(ws + 2899968);                // 4 MB
  float* w_chan   = (float*)(ws + 7094272);                // 4 MB
  bf16*  Wt_att   = (bf16*)(ws + 11288576);                // 2 MB
  bf16*  Wct      = (bf16*)(ws + 13385728);                // 224 KB  (end ~13.0 MiB)

  k_transpose_watt<<<2048, 256, 0, stream>>>(W_att, Wt_att);
  k_transpose_wch<<<448, 256, 0, stream>>>(W_ch, Wct);
  k_ph<<<dim3(2, 128), 256, 0, stream>>>(h, W_h, b_h, p_h);
  k_spatial<<<BL / 64, 256, 0, stream>>>(att, Wt_att, b_att, p_h, w_alpha, logits_s);
  k_channel<<<dim3(16, 1024), 256, 0, stream>>>(att, Wct, b_ch, p_h, w_beta, logits_c);
  k_softmax_s<<<1024, 256, 0, stream>>>(logits_s, out_wspat);
  k_softmax_c<<<1024, 256, 0, stream>>>(logits_c, w_chan);
  k_weighted<<<1024, 256, 0, stream>>>(att, out_wspat, w_chan, out_ws, out_wc);
}

// Round 2
// 2170.915 us; speedup vs baseline: 1.2337x; 1.2337x over previous
//
#include <hip/hip_runtime.h>
#include <cstdint>
#include <cstddef>

// ---------------------------------------------------------------------------
// DualAttention: B=1024, L=196, H=1024, A=512
//   spatial  = att @ W_att             [B,L,A] (fused)
//   channel  = att^T_l @ W_ch          [B,H,A] (fused)
//   logits_s = tanh(spatial+p_h).w_alpha -> softmax_L -> w_spatial
//   logits_c = tanh(channel+p_h).w_beta  -> softmax_H -> w_channel
//   out0 = sum_l w_spatial*att [B,H]; out1 = sum_h w_channel*att [B,L]; out2 = w_spatial
// GEMM structure (m97-style): B-operand = pre-panelized bf16 weights, staged
// via global_load_lds (16B) into linear LDS with baked XOR-slot swizzle;
// A-operand = reg-staged fp32->bf16 into 72B-stride LDS (conflict-free b64).
// ---------------------------------------------------------------------------

#define DEVI __device__ __forceinline__

typedef __bf16 bf16;
typedef bf16 bf16x4 __attribute__((ext_vector_type(4)));
typedef bf16 bf16x8 __attribute__((ext_vector_type(8)));
typedef float f32x4 __attribute__((ext_vector_type(4)));
typedef unsigned int uint32;

static constexpr int Bb = 1024;
static constexpr int Ll = 196;
static constexpr int Hh = 1024;
static constexpr int Aa = 512;
static constexpr int BL = Bb * Ll;        // 200704
static constexpr int LPAD = 224;          // 7*32

// LDS: B panel [512 rows][64B] linear at 0 (global_load_lds dest),
//      A tile  [64 rows][72B stride] at 32768.
#define AOFF 32768
#define ASTR 72
#define LDSZ (32768 + 64 * ASTR)

DEVI void async16(const void* g, void* l) {
  __builtin_amdgcn_global_load_lds(
      (const __attribute__((address_space(1))) void*)g,
      (__attribute__((address_space(3))) void*)l, 16, 0, 0);
}

DEVI float fast_tanh(float x) {
  float e = __expf(2.f * x);
  return 1.f - 2.f * __builtin_amdgcn_rcpf(e + 1.f);
}

DEVI uint32 packbf2(float a, float b) {
  union { bf16 h; unsigned short u; } x, y;
  x.h = (bf16)a; y.h = (bf16)b;
  return (uint32)x.u | ((uint32)y.u << 16);
}

// --------------------- weight panel builders (run once) --------------------
// Wt panels: [k0/32][a=0..511][64B], 16B slot s holds k = 32*panel+8*(s^g(a))+j,
// g(a) = (a>>1)&3.  Source W_att[k][a] fp32.
__global__ void k_build_wt(const float* __restrict__ W, bf16* __restrict__ P) {
  int idx = blockIdx.x * 256 + threadIdx.x;      // 65536 = 512a * 128 k-octs
  int a = idx & 511;
  int ko = (idx >> 9) << 3;                      // 0,8,...,1016
  bf16x8 v;
#pragma unroll
  for (int j = 0; j < 8; ++j) v[j] = (bf16)W[(size_t)(ko + j) * 512 + a];
  int panel = ko >> 5;
  int slot = ((ko >> 3) & 3) ^ ((a >> 1) & 3);
  *reinterpret_cast<bf16x8*>((char*)P + (size_t)panel * 32768 + a * 64 + slot * 16) = v;
}

// Wct panels: [l0/32][a][64B], k = l (zero-padded past 196). Source W_ch[l][a].
__global__ void k_build_wct(const float* __restrict__ W, bf16* __restrict__ P) {
  int idx = blockIdx.x * 256 + threadIdx.x;      // 14336 = 512a * 28 l-octs
  int a = idx & 511;
  int lo = (idx >> 9) << 3;                      // 0..216
  bf16x8 v;
#pragma unroll
  for (int j = 0; j < 8; ++j)
    v[j] = (lo + j < Ll) ? (bf16)W[(size_t)(lo + j) * 512 + a] : (bf16)0.f;
  int panel = lo >> 5;
  int slot = ((lo >> 3) & 3) ^ ((a >> 1) & 3);
  *reinterpret_cast<bf16x8*>((char*)P + (size_t)panel * 32768 + a * 64 + slot * 16) = v;
}

// ------------------------------- p_h = h@W_h -------------------------------
__global__ void k_ph(const float* __restrict__ h, const float* __restrict__ W_h,
                     const float* __restrict__ b_h, float* __restrict__ p_h) {
  int a = blockIdx.x * 256 + threadIdx.x;
  int b0 = blockIdx.y * 8;
  float acc[8] = {0.f, 0.f, 0.f, 0.f, 0.f, 0.f, 0.f, 0.f};
  for (int k = 0; k < 1024; ++k) {
    float w = W_h[(size_t)k * 512 + a];
#pragma unroll
    for (int i = 0; i < 8; ++i) acc[i] += h[(size_t)(b0 + i) * 1024 + k] * w;
  }
#pragma unroll
  for (int i = 0; i < 8; ++i) p_h[(size_t)(b0 + i) * 512 + a] = acc[i] + b_h[a];
}

// ---------------- spatial branch: fused GEMM + tanh-dot reduce -------------
// grid = BL/64 = 3136, 256 threads; block tile 64(BL-rows) x 512(a), K=1024.
__launch_bounds__(256)
__global__ void k_spatial(const float* __restrict__ att, const bf16* __restrict__ WtP,
                          const float* __restrict__ b_att, const float* __restrict__ p_h,
                          const float* __restrict__ w_alpha, float* __restrict__ logits_s) {
  __shared__ alignas(1024) char lds[LDSZ];
  const int tid = threadIdx.x;
  const int lane = tid & 63;
  const int wn = tid >> 6;
  const int l15 = lane & 15, l4 = lane >> 4;
  const size_t row0 = (size_t)blockIdx.x * 64;
  const int slotB = ((l4 ^ ((l15 >> 1) & 3)) << 4);   // baked-swizzle read slot
  const int ar = tid >> 2;                            // A-stage: row 0..63
  const int aks = (tid & 3) << 3;                     // k-offset 0,8,16,24

  f32x4 acc[4][8];
#pragma unroll
  for (int m = 0; m < 4; ++m)
#pragma unroll
    for (int n = 0; n < 8; ++n) acc[m][n] = f32x4{0.f, 0.f, 0.f, 0.f};

  for (int k0 = 0; k0 < 1024; k0 += 32) {
    // B: async-copy 32KB panel (linear, swizzle pre-baked)
    const char* bsrc = (const char*)WtP + (size_t)(k0 >> 5) * 32768;
#pragma unroll
    for (int i = 0; i < 8; ++i) {
      int c = (i << 2) + wn;
      async16(bsrc + c * 1024 + lane * 16, &lds[c * 1024]);
    }
    // A: reg-stage fp32 -> bf16, 72B stride
    const float* ap = att + (row0 + ar) * 1024 + k0 + aks;
    float4 v0 = *reinterpret_cast<const float4*>(ap);
    float4 v1 = *reinterpret_cast<const float4*>(ap + 4);
    bf16x4 w0 = {(bf16)v0.x, (bf16)v0.y, (bf16)v0.z, (bf16)v0.w};
    bf16x4 w1 = {(bf16)v1.x, (bf16)v1.y, (bf16)v1.z, (bf16)v1.w};
    *reinterpret_cast<bf16x4*>(&lds[AOFF + ar * ASTR + (aks << 1)]) = w0;
    *reinterpret_cast<bf16x4*>(&lds[AOFF + ar * ASTR + (aks << 1) + 8]) = w1;
    __syncthreads();

    bf16x8 af[4];
#pragma unroll
    for (int m = 0; m < 4; ++m) {
      int base = AOFF + (m * 16 + l15) * ASTR + (l4 << 4);
      bf16x4 lo = *reinterpret_cast<const bf16x4*>(&lds[base]);
      bf16x4 hi = *reinterpret_cast<const bf16x4*>(&lds[base + 8]);
      af[m] = __builtin_shufflevector(lo, hi, 0, 1, 2, 3, 4, 5, 6, 7);
    }
#pragma unroll
    for (int n = 0; n < 8; ++n) {
      bf16x8 bv = *reinterpret_cast<const bf16x8*>(
          &lds[(wn * 128 + n * 16 + l15) * 64 + slotB]);
#pragma unroll
      for (int m = 0; m < 4; ++m)
        acc[m][n] = __builtin_amdgcn_mfma_f32_16x16x32_bf16(af[m], bv, acc[m][n], 0, 0, 0);
    }
    __syncthreads();
  }

  // epilogue
  float wa[8], ba[8], ph0[8], ph1[8];
  int cols[8];
  unsigned b0i = (unsigned)row0 / 196u;
  unsigned b1i = (unsigned)(row0 + 63) / 196u;
  unsigned bnd = (b0i + 1) * 196u;
#pragma unroll
  for (int n = 0; n < 8; ++n) {
    int a = wn * 128 + n * 16 + l15;
    cols[n] = a;
    wa[n] = w_alpha[a];
    ba[n] = b_att[a];
    ph0[n] = p_h[(size_t)b0i * 512 + a];
    ph1[n] = p_h[(size_t)b1i * 512 + a];
  }
  float* red = reinterpret_cast<float*>(lds);    // [4][64]
#pragma unroll
  for (int m = 0; m < 4; ++m) {
#pragma unroll
    for (int j = 0; j < 4; ++j) {
      int rloc = m * 16 + l4 * 4 + j;
      unsigned R = (unsigned)row0 + rloc;
      bool hib = R >= bnd;
      float s = 0.f;
#pragma unroll
      for (int n = 0; n < 8; ++n)
        s += fast_tanh(acc[m][n][j] + ba[n] + (hib ? ph1[n] : ph0[n])) * wa[n];
      s += __shfl_xor(s, 1);
      s += __shfl_xor(s, 2);
      s += __shfl_xor(s, 4);
      s += __shfl_xor(s, 8);
      if (l15 == 0) red[wn * 64 + rloc] = s;
    }
  }
  __syncthreads();
  if (tid < 64)
    logits_s[row0 + tid] = red[tid] + red[64 + tid] + red[128 + tid] + red[192 + tid];
}

// ---------------- channel branch: fused GEMM + tanh-dot reduce -------------
// grid = (16 h-tiles, 1024 b); D[h,a] = sum_l att[b][l][h]*W_ch[l][a], K=224.
// A-transpose via pair-packed u32 LDS writes (coalesced float4 global reads).
__launch_bounds__(256)
__global__ void k_channel(const float* __restrict__ att, const bf16* __restrict__ WctP,
                          const float* __restrict__ b_ch, const float* __restrict__ p_h,
                          const float* __restrict__ w_beta, float* __restrict__ logits_c) {
  __shared__ alignas(1024) char lds[LDSZ];
  const int tid = threadIdx.x;
  const int lane = tid & 63;
  const int wn = tid >> 6;
  const int l15 = lane & 15, l4 = lane >> 4;
  const int b = blockIdx.y;
  const int h0 = blockIdx.x * 64;
  const float* attb = att + (size_t)b * Ll * 1024;
  const int slotB = ((l4 ^ ((l15 >> 1) & 3)) << 4);
  const int lsub = tid >> 4;                     // l-pair 0..15
  const int hq4 = (tid & 15) << 2;               // h base 0,4,...,60

  f32x4 acc[4][8];
#pragma unroll
  for (int m = 0; m < 4; ++m)
#pragma unroll
    for (int n = 0; n < 8; ++n) acc[m][n] = f32x4{0.f, 0.f, 0.f, 0.f};

  for (int t7 = 0; t7 < 7; ++t7) {
    const int l0 = t7 * 32;
    // B: async-copy Wct panel
    const char* bsrc = (const char*)WctP + (size_t)t7 * 32768;
#pragma unroll
    for (int i = 0; i < 8; ++i) {
      int c = (i << 2) + wn;
      async16(bsrc + c * 1024 + lane * 16, &lds[c * 1024]);
    }
    // A: transpose-stage att[b][l][h0..h0+63] -> lds[h][l] as u32 l-pairs
    {
      int lg = l0 + 2 * lsub;
      float4 va = {0.f, 0.f, 0.f, 0.f}, vb = {0.f, 0.f, 0.f, 0.f};
      if (lg < Ll)     va = *reinterpret_cast<const float4*>(&attb[(size_t)lg * 1024 + h0 + hq4]);
      if (lg + 1 < Ll) vb = *reinterpret_cast<const float4*>(&attb[(size_t)(lg + 1) * 1024 + h0 + hq4]);
      uint32 p0 = packbf2(va.x, vb.x), p1 = packbf2(va.y, vb.y);
      uint32 p2 = packbf2(va.z, vb.z), p3 = packbf2(va.w, vb.w);
      char* abase = &lds[AOFF + hq4 * ASTR + (lsub << 2)];
      *reinterpret_cast<uint32*>(abase) = p0;
      *reinterpret_cast<uint32*>(abase + ASTR) = p1;
      *reinterpret_cast<uint32*>(abase + 2 * ASTR) = p2;
      *reinterpret_cast<uint32*>(abase + 3 * ASTR) = p3;
    }
    __syncthreads();

    bf16x8 af[4];
#pragma unroll
    for (int m = 0; m < 4; ++m) {
      int base = AOFF + (m * 16 + l15) * ASTR + (l4 << 4);
      bf16x4 lo = *reinterpret_cast<const bf16x4*>(&lds[base]);
      bf16x4 hi = *reinterpret_cast<const bf16x4*>(&lds[base + 8]);
      af[m] = __builtin_shufflevector(lo, hi, 0, 1, 2, 3, 4, 5, 6, 7);
    }
#pragma unroll
    for (int n = 0; n < 8; ++n) {
      bf16x8 bv = *reinterpret_cast<const bf16x8*>(
          &lds[(wn * 128 + n * 16 + l15) * 64 + slotB]);
#pragma unroll
      for (int m = 0; m < 4; ++m)
        acc[m][n] = __builtin_amdgcn_mfma_f32_16x16x32_bf16(af[m], bv, acc[m][n], 0, 0, 0);
    }
    __syncthreads();
  }

  // epilogue
  float wb[8], bc[8], ph[8];
#pragma unroll
  for (int n = 0; n < 8; ++n) {
    int a = wn * 128 + n * 16 + l15;
    wb[n] = w_beta[a];
    bc[n] = b_ch[a];
    ph[n] = p_h[(size_t)b * 512 + a];
  }
  float* red = reinterpret_cast<float*>(lds);
#pragma unroll
  for (int m = 0; m < 4; ++m) {
#pragma unroll
    for (int j = 0; j < 4; ++j) {
      int rloc = m * 16 + l4 * 4 + j;
      float s = 0.f;
#pragma unroll
      for (int n = 0; n < 8; ++n)
        s += fast_tanh(acc[m][n][j] + bc[n] + ph[n]) * wb[n];
      s += __shfl_xor(s, 1);
      s += __shfl_xor(s, 2);
      s += __shfl_xor(s, 4);
      s += __shfl_xor(s, 8);
      if (l15 == 0) red[wn * 64 + rloc] = s;
    }
  }
  __syncthreads();
  if (tid < 64)
    logits_c[(size_t)b * 1024 + h0 + tid] =
        red[tid] + red[64 + tid] + red[128 + tid] + red[192 + tid];
}

// ------------------------------- softmaxes ---------------------------------
__global__ void k_softmax_s(const float* __restrict__ logits, float* __restrict__ wout) {
  int b = blockIdx.x, t = threadIdx.x;
  __shared__ float sm[8];
  float x = (t < Ll) ? logits[(size_t)b * Ll + t] : -1e30f;
  float m = x;
#pragma unroll
  for (int o = 32; o; o >>= 1) m = fmaxf(m, __shfl_xor(m, o));
  if ((t & 63) == 0) sm[t >> 6] = m;
  __syncthreads();
  m = fmaxf(fmaxf(sm[0], sm[1]), fmaxf(sm[2], sm[3]));
  float e = (t < Ll) ? __expf(x - m) : 0.f;
  float s = e;
#pragma unroll
  for (int o = 32; o; o >>= 1) s += __shfl_xor(s, o);
  if ((t & 63) == 0) sm[4 + (t >> 6)] = s;
  __syncthreads();
  s = sm[4] + sm[5] + sm[6] + sm[7];
  if (t < Ll) wout[(size_t)b * Ll + t] = e / s;
}

__global__ void k_softmax_c(const float* __restrict__ logits, float* __restrict__ wout) {
  int b = blockIdx.x, t = threadIdx.x;
  __shared__ float sm[8];
  float4 x = *reinterpret_cast<const float4*>(&logits[(size_t)b * 1024 + (t << 2)]);
  float m = fmaxf(fmaxf(x.x, x.y), fmaxf(x.z, x.w));
#pragma unroll
  for (int o = 32; o; o >>= 1) m = fmaxf(m, __shfl_xor(m, o));
  if ((t & 63) == 0) sm[t >> 6] = m;
  __syncthreads();
  m = fmaxf(fmaxf(sm[0], sm[1]), fmaxf(sm[2], sm[3]));
  float e0 = __expf(x.x - m), e1 = __expf(x.y - m);
  float e2 = __expf(x.z - m), e3 = __expf(x.w - m);
  float s = e0 + e1 + e2 + e3;
#pragma unroll
  for (int o = 32; o; o >>= 1) s += __shfl_xor(s, o);
  if ((t & 63) == 0) sm[4 + (t >> 6)] = s;
  __syncthreads();
  float r = 1.f / (sm[4] + sm[5] + sm[6] + sm[7]);
  float4 o4 = {e0 * r, e1 * r, e2 * r, e3 * r};
  *reinterpret_cast<float4*>(&wout[(size_t)b * 1024 + (t << 2)]) = o4;
}

// --------------- fused weighted sums: one pass over att --------------------
__launch_bounds__(256)
__global__ void k_weighted(const float* __restrict__ att, const float* __restrict__ wsp,
                           const float* __restrict__ wch, float* __restrict__ out_s,
                           float* __restrict__ out_c) {
  int b = blockIdx.x, t = threadIdx.x;
  int lane = t & 63, wave = t >> 6;
  __shared__ float wsl[Ll];
  __shared__ float chan[4][Ll];
  if (t < Ll) wsl[t] = wsp[(size_t)b * Ll + t];
  float4 wc = *reinterpret_cast<const float4*>(&wch[(size_t)b * 1024 + (t << 2)]);
  float4 accs = {0.f, 0.f, 0.f, 0.f};
  __syncthreads();
  const float* attb = att + (size_t)b * Ll * 1024;
  for (int l = 0; l < Ll; ++l) {
    float4 v = *reinterpret_cast<const float4*>(&attb[(size_t)l * 1024 + (t << 2)]);
    float w = wsl[l];
    accs.x += w * v.x; accs.y += w * v.y; accs.z += w * v.z; accs.w += w * v.w;
    float pc = wc.x * v.x + wc.y * v.y + wc.z * v.z + wc.w * v.w;
#pragma unroll
    for (int o = 32; o; o >>= 1) pc += __shfl_xor(pc, o);
    if (lane == 0) chan[wave][l] = pc;
  }
  *reinterpret_cast<float4*>(&out_s[(size_t)b * 1024 + (t << 2)]) = accs;
  __syncthreads();
  if (t < Ll)
    out_c[(size_t)b * Ll + t] = chan[0][t] + chan[1][t] + chan[2][t] + chan[3][t];
}

// ------------------------------- launcher ----------------------------------
extern "C" void kernel_launch(void* const* d_in, const int* in_sizes, int n_in,
                              void* d_out, int out_size, void* d_ws, size_t ws_size,
                              hipStream_t stream) {
  (void)in_sizes; (void)n_in; (void)out_size; (void)ws_size;
  const float* att     = (const float*)d_in[0];
  const float* h       = (const float*)d_in[1];
  const float* W_att   = (const float*)d_in[2];
  const float* b_att   = (const float*)d_in[3];
  const float* W_h     = (const float*)d_in[4];
  const float* b_h     = (const float*)d_in[5];
  const float* w_alpha = (const float*)d_in[6];
  const float* W_ch    = (const float*)d_in[8];
  const float* b_ch    = (const float*)d_in[9];
  const float* w_beta  = (const float*)d_in[10];
  // d_in[7] b_alpha, d_in[11] b_beta: softmax-shift-invariant, unused

  float* out_ws    = (float*)d_out;                       // [B,H]
  float* out_wc    = out_ws + (size_t)Bb * Hh;            // [B,L]
  float* out_wspat = out_wc + (size_t)Bb * Ll;            // [B,L]

  char* ws = (char*)d_ws;
  float* p_h      = (float*)(ws);                          // 2 MB
  float* logits_s = (float*)(ws + 2097152);                // 802816 B
  float* logits_c = (float*)(ws + 2899968);                // 4 MB
  float* w_chan   = (float*)(ws + 7094272);                // 4 MB
  bf16*  WtP      = (bf16*)(ws + 11288576);                // 1 MB (32 panels)
  bf16*  WctP     = (bf16*)(ws + 12337152);                // 224 KB (7 panels)

  k_build_wt<<<256, 256, 0, stream>>>(W_att, WtP);
  k_build_wct<<<56, 256, 0, stream>>>(W_ch, WctP);
  k_ph<<<dim3(2, 128), 256, 0, stream>>>(h, W_h, b_h, p_h);
  k_spatial<<<BL / 64, 256, 0, stream>>>(att, WtP, b_att, p_h, w_alpha, logits_s);
  k_channel<<<dim3(16, 1024), 256, 0, stream>>>(att, WctP, b_ch, p_h, w_beta, logits_c);
  k_softmax_s<<<1024, 256, 0, stream>>>(logits_s, out_wspat);
  k_softmax_c<<<1024, 256, 0, stream>>>(logits_c, w_chan);
  k_weighted<<<1024, 256, 0, stream>>>(att, out_wspat, w_chan, out_ws, out_wc);
}